// Round 5
// baseline (213.561 us; speedup 1.0000x reference)
//
#include <hip/hip_runtime.h>

#define CC 8
#define HH 256
#define WW 512
#define KK 9
#define SEGW 128
#define XF 144   // LDS floats per (wave,buf,ch): 136 used, padded

// Occupancy build: grid 2048 (4 w-segs of 128 px), 2 px/lane, launch_bounds
// (256,8) -> 8 blocks/CU = 32 waves/CU (2x the R0-R3 cap). R0-R3 showed the
// kernel is latency-bound and schedule-invariant at fixed TLP; R4 showed
// direct-global loads starve VGPRs. So: wave-private LDS staging (small reg
// footprint) + maximum TLP.
__global__ __launch_bounds__(256, 8) void dynfilter_kernel(
    const float* __restrict__ x,
    const float* __restrict__ filt,
    const float* __restrict__ fbias,
    float* __restrict__ out)
{
    __shared__ __align__(16) float xs[4][2][2][XF];  // 9216 B/block

    const int tid  = threadIdx.x;
    const int wv   = tid >> 6;          // wave -> channels {2wv, 2wv+1}
    const int lane = tid & 63;

    // XCD-aware bijective swizzle: nwg=2048, 256 contiguous work items/XCD.
    const int bid0 = blockIdx.x;
    const int bid  = ((bid0 & 7) << 8) | (bid0 >> 3);

    const int seg = bid & 3;            // 4 segments of 128 px
    const int h   = (bid >> 2) & 255;
    const int n   = bid >> 10;

    const int w0      = seg * SEGW + (lane << 1);   // 2 px per lane
    const int wstage0 = seg * SEGW - 4;

    const size_t HW = (size_t)HH * WW;
    const int c0 = wv << 1;

    const float* xr0  = x + (size_t)(n * CC + c0)     * HW + wstage0;
    const float* xr1  = x + (size_t)(n * CC + c0 + 1) * HW + wstage0;
    const float* fptr = filt + ((size_t)(n * 81) * HH + h) * WW + w0;

    float acc0[2], acc1[2];
    {
        const float2 b2 = *(const float2*)(fbias + ((size_t)(n * HH + h)) * WW + w0);
        acc0[0] = b2.x; acc0[1] = b2.y;
        acc1[0] = b2.x; acc1[1] = b2.y;
    }

    // staging chunk coords (window = 136 floats: main 128 + tail 8)
    const int wmain = wstage0 + (lane << 1);         // all lanes, float2
    const int wtail = wstage0 + 128 + (lane << 1);   // lanes 0-3, float2
    const bool main_ok = (unsigned)wmain < (unsigned)WW;  // fails: seg0 lanes 0,1
    const bool tail_ok = (lane < 4) && ((unsigned)wtail < (unsigned)WW);

    // ---- prologue: stage row h-4 into buf 0 (wave-private, no barrier) ----
    {
        const int hh = h - 4;
        const bool rowok = hh >= 0;
        const float* s0 = xr0 + (size_t)hh * WW;
        const float* s1 = xr1 + (size_t)hh * WW;
        float2 m0 = make_float2(0.f, 0.f), m1 = m0, t0 = m0, t1 = m0;
        if (rowok && main_ok) { m0 = *(const float2*)(s0 + (lane << 1));       m1 = *(const float2*)(s1 + (lane << 1)); }
        if (rowok && tail_ok) { t0 = *(const float2*)(s0 + 128 + (lane << 1)); t1 = *(const float2*)(s1 + 128 + (lane << 1)); }
        *(float2*)&xs[wv][0][0][lane << 1] = m0;
        *(float2*)&xs[wv][0][1][lane << 1] = m1;
        if (lane < 4) {
            *(float2*)&xs[wv][0][0][128 + (lane << 1)] = t0;
            *(float2*)&xs[wv][0][1][128 + (lane << 1)] = t1;
        }
    }

    // CRITICAL: compiler auto-unrolls trip-count-9 loops, then hoists all 81
    // filter loads -> VGPR blowup + spill. unroll(disable) is the fix.
    #pragma clang loop unroll(disable)
    for (int i = 0; i < KK; ++i) {
        const int buf = i & 1;

        // 1) issue next-row x staging loads first (consumed at step 5)
        float2 m0 = make_float2(0.f, 0.f), m1 = m0, t0 = m0, t1 = m0;
        if (i < KK - 1) {
            const int hh = h - 3 + i;
            const bool rowok = (unsigned)hh < (unsigned)HH;
            const float* s0 = xr0 + (size_t)hh * WW;
            const float* s1 = xr1 + (size_t)hh * WW;
            if (rowok && main_ok) { m0 = *(const float2*)(s0 + (lane << 1));       m1 = *(const float2*)(s1 + (lane << 1)); }
            if (rowok && tail_ok) { t0 = *(const float2*)(s0 + 128 + (lane << 1)); t1 = *(const float2*)(s1 + 128 + (lane << 1)); }
        }

        // 2) filter taps for row i: 9 coalesced float2 loads (2 px per lane)
        float2 f[9];
        {
            const float* fi = fptr + (size_t)i * KK * HW;
            #pragma unroll
            for (int j = 0; j < 9; ++j) f[j] = *(const float2*)(fi + (size_t)j * HW);
        }

        // 3) x window from wave-private LDS: 10 floats per channel,
        //    rel offset [2*lane, 2*lane+10)
        float v0[10], v1[10];
        {
            const float* p0 = &xs[wv][buf][0][lane << 1];
            const float* p1 = &xs[wv][buf][1][lane << 1];
            #pragma unroll
            for (int k = 0; k < 5; ++k) {
                float2 u0 = *(const float2*)(p0 + 2 * k);
                float2 u1 = *(const float2*)(p1 + 2 * k);
                v0[2*k] = u0.x; v0[2*k+1] = u0.y;
                v1[2*k] = u1.x; v1[2*k+1] = u1.y;
            }
        }

        // 4) 36 FMAs (2 ch x 2 px x 9 taps)
        #pragma unroll
        for (int j = 0; j < 9; ++j) {
            acc0[0] = fmaf(f[j].x, v0[j],   acc0[0]);
            acc0[1] = fmaf(f[j].y, v0[j+1], acc0[1]);
            acc1[0] = fmaf(f[j].x, v1[j],   acc1[0]);
            acc1[1] = fmaf(f[j].y, v1[j+1], acc1[1]);
        }

        // 5) store staged row into the other wave-private buffer
        if (i < KK - 1) {
            *(float2*)&xs[wv][buf ^ 1][0][lane << 1] = m0;
            *(float2*)&xs[wv][buf ^ 1][1][lane << 1] = m1;
            if (lane < 4) {
                *(float2*)&xs[wv][buf ^ 1][0][128 + (lane << 1)] = t0;
                *(float2*)&xs[wv][buf ^ 1][1][128 + (lane << 1)] = t1;
            }
        }
    }

    {
        *(float2*)(out + ((size_t)(n * CC + c0)     * HH + h) * WW + w0) =
            make_float2(acc0[0], acc0[1]);
        *(float2*)(out + ((size_t)(n * CC + c0 + 1) * HH + h) * WW + w0) =
            make_float2(acc1[0], acc1[1]);
    }
}

extern "C" void kernel_launch(void* const* d_in, const int* in_sizes, int n_in,
                              void* d_out, int out_size, void* d_ws, size_t ws_size,
                              hipStream_t stream) {
    const float* x  = (const float*)d_in[0];
    const float* f  = (const float*)d_in[1];
    const float* fb = (const float*)d_in[2];
    float* o = (float*)d_out;
    hipLaunchKernelGGL(dynfilter_kernel, dim3(2048), dim3(256), 0, stream,
                       x, f, fb, o);
}

// Round 6
// 148.716 us; speedup vs baseline: 1.4360x; 1.4360x over previous
//
#include <hip/hip_runtime.h>

#define CC 8
#define HH 256
#define WW 512
#define KK 9
#define XF 272   // LDS floats per (wave,buf): 264 used, padded to 16B multiple

// TLP build: grid 2048 = n(2) x h(256) x seg(2) x cgrp(2); each block owns 4
// channels (1 per wave), 4 px/lane over a 256-px segment. launch_bounds(256,6)
// -> 84 VGPR budget, 6 blocks/CU = 24 waves/CU (1.5x the R0-R3 plateau's 16).
// Per-wave body keeps the proven R2/R3 ILP shape: f[9] float4 in flight +
// wave-private LDS x-staging, no barriers. R4/R5 lesson: never cut per-wave
// in-flight loads; R5 lesson: never force the allocator below ~75 VGPR.
__global__ __launch_bounds__(256, 6) void dynfilter_kernel(
    const float* __restrict__ x,
    const float* __restrict__ filt,
    const float* __restrict__ fbias,
    float* __restrict__ out)
{
    __shared__ __align__(16) float xs[4][2][XF];   // 8704 B/block

    const int tid  = threadIdx.x;
    const int wv   = tid >> 6;          // wave -> channel cgrp*4 + wv
    const int lane = tid & 63;

    // XCD-aware bijective swizzle: nwg=2048 -> 256 contiguous work items/XCD.
    // cgrp-pair work items (bid, bid^1) map to dispatch ids 8 apart -> same
    // XCD -> duplicated filter loads hit the same L2.
    const int bid0 = blockIdx.x;
    const int bid  = ((bid0 & 7) << 8) | (bid0 >> 3);

    const int cgrp = bid & 1;
    const int seg  = (bid >> 1) & 1;
    const int h    = (bid >> 2) & 255;
    const int n    = bid >> 10;

    const int w0      = seg * 256 + (lane << 2);   // 4 px per lane
    const int wstage0 = seg * 256 - 4;

    const size_t HW = (size_t)HH * WW;
    const int c = (cgrp << 2) + wv;

    const float* xrow = x + (size_t)(n * CC + c) * HW + wstage0;
    const float* fptr = filt + ((size_t)(n * 81) * HH + h) * WW + w0;

    float acc[4];
    {
        const float4 b4 = *(const float4*)(fbias + ((size_t)(n * HH + h)) * WW + w0);
        acc[0] = b4.x; acc[1] = b4.y; acc[2] = b4.z; acc[3] = b4.w;
    }

    // staging chunk validity (window = 264 floats: main 256 + tail 8)
    const bool main_ok = (unsigned)(wstage0 + (lane << 2)) < (unsigned)WW;        // fails only seg0 lane0
    const bool tail_ok = (lane < 2) && ((unsigned)(wstage0 + 256 + (lane << 2)) < (unsigned)WW); // fails seg1 lane1

    // ---- prologue: stage row h-4 into buf 0 (wave-private, no barrier) ----
    {
        const int hh = h - 4;
        const bool rowok = hh >= 0;
        const float* src = xrow + (size_t)hh * WW;
        float4 sm = make_float4(0.f, 0.f, 0.f, 0.f), st = sm;
        if (rowok && main_ok) sm = *(const float4*)(src + (lane << 2));
        if (rowok && tail_ok) st = *(const float4*)(src + 256 + (lane << 2));
        *(float4*)&xs[wv][0][lane << 2] = sm;
        if (lane < 2) *(float4*)&xs[wv][0][256 + (lane << 2)] = st;
    }

    // CRITICAL: compiler auto-unrolls trip-count-9 loops, then hoists all 81
    // filter loads -> VGPR blowup + spill. unroll(disable) is the fix.
    #pragma clang loop unroll(disable)
    for (int i = 0; i < KK; ++i) {
        const int buf = i & 1;

        // 1) issue next-row x staging loads first (consumed at step 5)
        float4 sm = make_float4(0.f, 0.f, 0.f, 0.f), st = sm;
        if (i < KK - 1) {
            const int hh = h - 3 + i;
            const bool rowok = (unsigned)hh < (unsigned)HH;
            const float* src = xrow + (size_t)hh * WW;
            if (rowok && main_ok) sm = *(const float4*)(src + (lane << 2));
            if (rowok && tail_ok) st = *(const float4*)(src + 256 + (lane << 2));
        }

        // 2) filter taps for row i: 9 coalesced float4 loads (4 px per lane)
        float4 f[9];
        {
            const float* fi = fptr + (size_t)i * KK * HW;
            #pragma unroll
            for (int j = 0; j < 9; ++j) f[j] = *(const float4*)(fi + (size_t)j * HW);
        }

        // 3) x window from wave-private LDS: 12 floats (rel start = 4*lane)
        float v[12];
        {
            const float* p = &xs[wv][buf][lane << 2];
            float4 u;
            u = *(const float4*)(p + 0); v[0]=u.x; v[1]=u.y; v[2] =u.z; v[3] =u.w;
            u = *(const float4*)(p + 4); v[4]=u.x; v[5]=u.y; v[6] =u.z; v[7] =u.w;
            u = *(const float4*)(p + 8); v[8]=u.x; v[9]=u.y; v[10]=u.z; v[11]=u.w;
        }

        // 4) 36 FMAs (1 ch x 4 px x 9 taps)
        #pragma unroll
        for (int j = 0; j < 9; ++j) {
            acc[0] = fmaf(f[j].x, v[j+0], acc[0]);
            acc[1] = fmaf(f[j].y, v[j+1], acc[1]);
            acc[2] = fmaf(f[j].z, v[j+2], acc[2]);
            acc[3] = fmaf(f[j].w, v[j+3], acc[3]);
        }

        // 5) store staged row into the other wave-private buffer
        if (i < KK - 1) {
            *(float4*)&xs[wv][buf ^ 1][lane << 2] = sm;
            if (lane < 2) *(float4*)&xs[wv][buf ^ 1][256 + (lane << 2)] = st;
        }
    }

    *(float4*)(out + ((size_t)(n * CC + c) * HH + h) * WW + w0) =
        make_float4(acc[0], acc[1], acc[2], acc[3]);
}

extern "C" void kernel_launch(void* const* d_in, const int* in_sizes, int n_in,
                              void* d_out, int out_size, void* d_ws, size_t ws_size,
                              hipStream_t stream) {
    const float* x  = (const float*)d_in[0];
    const float* f  = (const float*)d_in[1];
    const float* fb = (const float*)d_in[2];
    float* o = (float*)d_out;
    hipLaunchKernelGGL(dynfilter_kernel, dim3(2048), dim3(256), 0, stream,
                       x, f, fb, o);
}